// Round 17
// baseline (94.937 us; speedup 1.0000x reference)
//
#include <hip/hip_runtime.h>

typedef _Float16 f16;
typedef _Float16 f16x8 __attribute__((ext_vector_type(8)));
typedef __fp16 hf16x2 __attribute__((ext_vector_type(2)));
typedef float f32x4 __attribute__((ext_vector_type(4)));
typedef float f32x16 __attribute__((ext_vector_type(16)));

// ---------------- d_ws layout (32x32x16 MFMA fragment order) ----------------
// [0, 262144) : f16 weight images, per-lane A-fragment order for
//   mfma_f32_32x32x16_f16. frag f = T*nks + m at imgbase + (f*64+lane)*16 + j*2
//   holds W[k_logical][och_out = 32T + (lane&31)], natural k_raw = 16m +
//   8*(lane>>5) + j.
//     k_logical = k_raw          for L1 (input built raw by L0)
//     k_logical = klog32(k_raw)  for L2..L7, C0, C1, C2 (in-register chaining;
//       C row=(reg&3)+8*(reg>>2)+4*(lane>>5) vs B k=8*(lane>>5)+j mismatch is
//       exactly a swap of bits 2<->3 of the within-16 k index)
//   L1..L7 (128x128, nks=8): i*32768 | C0h (64x128): 229376
//   C1 (64x64, nks=4): 245760 | C2: 253952
// [262144, +10240) : fp32 params block (identical to R11..R15):
//   0 b0f[128] | 128 W0p[3][128] | 512 b5f[128] | 640 W5p[3][128]
//   1024 db1 1152 db2 1280 db3 1408 db4 1536 db6 1664 db7 (x128)
//   1792 cb0[64] | 1856 cWv[3][64] | 2048 cb1[64] | 2112 cb2[64]
//   2176 sW[128] | 2304 sb | 2308 rWT[3][64] | 2500 rb[3]
#define WS_PARAMS 262144

struct Ptrs { const float* p[29]; };

__device__ __forceinline__ int klog32(int q) {
  return (q & ~12) | ((q & 4) << 1) | ((q & 8) >> 1);
}

// ---------------------------------------------------------------------------
// Prepass. Params block verbatim; weight images in 32x32x16 fragment order.
// ---------------------------------------------------------------------------
__global__ void nerf_prep(Ptrs ptrs, char* __restrict__ ws) {
  const int t = threadIdx.x;
  if (blockIdx.x == 0) {
    float* P = (float*)(ws + WS_PARAMS);
    const float* cond = ptrs.p[1];
    const float* dW0 = ptrs.p[3];  const float* db0 = ptrs.p[4];
    const float* dW5 = ptrs.p[13]; const float* db5 = ptrs.p[14];
    if (t < 128) {
      float a0 = db0[t], a5 = db5[t];
      for (int k = 0; k < 64; ++k) {
        const float c = cond[k];
        a0 += c * dW0[(3 + k) * 128 + t];
        a5 += c * dW5[(3 + k) * 128 + t];
      }
      P[t] = a0;          // b0f
      P[512 + t] = a5;    // b5f
      for (int k = 0; k < 3; ++k) {
        P[128 + k * 128 + t] = dW0[k * 128 + t];   // W0p
        P[640 + k * 128 + t] = dW5[k * 128 + t];   // W5p
      }
      P[1024 + t] = ptrs.p[6][t];    // db1
      P[1152 + t] = ptrs.p[8][t];    // db2
      P[1280 + t] = ptrs.p[10][t];   // db3
      P[1408 + t] = ptrs.p[12][t];   // db4
      P[1536 + t] = ptrs.p[16][t];   // db6
      P[1664 + t] = ptrs.p[18][t];   // db7
      P[2176 + t] = ptrs.p[19][t];   // sW
    }
    if (t < 64) {
      P[1792 + t] = ptrs.p[22][t];   // cb0
      for (int k = 0; k < 3; ++k)    // cWv = cW0 rows 128..130
        P[1856 + k * 64 + t] = ptrs.p[21][(128 + k) * 64 + t];
      P[2048 + t] = ptrs.p[24][t];   // cb1
      P[2112 + t] = ptrs.p[26][t];   // cb2
      for (int c = 0; c < 3; ++c)    // rWT[3][64]
        P[2308 + c * 64 + t] = ptrs.p[27][t * 3 + c];
    }
    if (t == 0) {
      P[2304] = ptrs.p[20][0];                 // sb
      P[2500] = ptrs.p[28][0];
      P[2501] = ptrs.p[28][1];
      P[2502] = ptrs.p[28][2];                 // rb
    }
    if (t < 3)  P[2305 + t] = 0.f;
    if (t < 57) P[2503 + t] = 0.f;
    return;
  }
  // 131072 f16 weight-fragment elements across blocks 1..512
  const int e = (blockIdx.x - 1) * 256 + t;
  float v; int dst;
  if (e < 114688) {                       // L1..L7 (128x128, 32 frags each)
    const int img = e >> 14, o = e & 16383;
    const int j = o & 7, lane = (o >> 3) & 63, m = (o >> 9) & 7, T = o >> 12;
    const int kraw = m * 16 + ((lane >> 5) << 3) + j;
    const int k = (img == 0) ? kraw : klog32(kraw);
    const int och = T * 32 + (lane & 31);
    v = ptrs.p[5 + 2 * img][(k + (img == 4 ? 67 : 0)) * 128 + och];
    dst = img * 32768 + (((T * 8 + m) * 64 + lane) << 4) + (j << 1);
  } else if (e < 122880) {                // C0h (64x128, 16 frags)
    const int o = e - 114688;
    const int j = o & 7, lane = (o >> 3) & 63, m = (o >> 9) & 7, T = o >> 12;
    const int k = klog32(m * 16 + ((lane >> 5) << 3) + j);
    const int och = T * 32 + (lane & 31);
    v = ptrs.p[21][k * 64 + och];
    dst = 229376 + (((T * 8 + m) * 64 + lane) << 4) + (j << 1);
  } else if (e < 126976) {                // C1 (64x64, 8 frags)
    const int o = e - 122880;
    const int j = o & 7, lane = (o >> 3) & 63, m = (o >> 9) & 3, T = o >> 11;
    const int k = klog32(m * 16 + ((lane >> 5) << 3) + j);
    const int och = T * 32 + (lane & 31);
    v = ptrs.p[23][k * 64 + och];
    dst = 245760 + (((T * 4 + m) * 64 + lane) << 4) + (j << 1);
  } else {                                // C2 (64x64, 8 frags)
    const int o = e - 126976;
    const int j = o & 7, lane = (o >> 3) & 63, m = (o >> 9) & 3, T = o >> 11;
    const int k = klog32(m * 16 + ((lane >> 5) << 3) + j);
    const int och = T * 32 + (lane & 31);
    v = ptrs.p[25][k * 64 + och];
    dst = 253952 + (((T * 4 + m) * 64 + lane) << 4) + (j << 1);
  }
  *(f16*)(ws + dst) = (f16)v;
}

// ---------------------------------------------------------------------------
// helpers
// ---------------------------------------------------------------------------
__device__ __forceinline__ void loadF4(f16x8* A, const char* __restrict__ img,
                                       int fb, int lane) {
#pragma unroll
  for (int i = 0; i < 4; ++i)
    A[i] = *(const f16x8*)(img + (((fb + i) * 64 + lane) << 4));
}

// pack two f32x4 -> f16x8 via cvt_pkrtz, then packed relu
__device__ __forceinline__ f16x8 packRelu(const f32x4 v0, const f32x4 v1) {
  const hf16x2 p0 = __builtin_amdgcn_cvt_pkrtz(v0[0], v0[1]);
  const hf16x2 p1 = __builtin_amdgcn_cvt_pkrtz(v0[2], v0[3]);
  const hf16x2 p2 = __builtin_amdgcn_cvt_pkrtz(v1[0], v1[1]);
  const hf16x2 p3 = __builtin_amdgcn_cvt_pkrtz(v1[2], v1[3]);
  f16x8 hb;
  hb[0] = (f16)p0[0]; hb[1] = (f16)p0[1]; hb[2] = (f16)p1[0]; hb[3] = (f16)p1[1];
  hb[4] = (f16)p2[0]; hb[5] = (f16)p2[1]; hb[6] = (f16)p3[0]; hb[7] = (f16)p3[1];
#pragma unroll
  for (int e2 = 0; e2 < 8; ++e2)
    hb[e2] = hb[e2] > (f16)0.f ? hb[e2] : (f16)0.f;
  return hb;
}

// ---------------------------------------------------------------------------
// Chunk: och-tile T, k-half KH (k-steps m = 4KH..4KH+3), 8 MFMAs (2 pt-tiles).
// KH==0 seeds acc via the MFMA C operand (bias16, + pos/view for INIT 1/2).
// ---------------------------------------------------------------------------
template<int T, int KH, int INIT>
__device__ __forceinline__ void qL32(const f16x8 B[2][8], f32x16 acc[2][4],
                                     const f16x8* A, const float* __restrict__ P,
                                     const float px[2][3],
                                     const float* __restrict__ vw2,
                                     int biasOff, int h4, int wbase) {
  if (KH == 0) {
    f32x4 bq[4];
#pragma unroll
    for (int q = 0; q < 4; ++q)
      bq[q] = *(const f32x4*)(P + biasOff + T * 32 + q * 8 + h4);
    f32x4 e0[4], e1[4], e2[4];
    if (INIT == 1) {
#pragma unroll
      for (int q = 0; q < 4; ++q) {
        e0[q] = *(const f32x4*)(P + 640 + T * 32 + q * 8 + h4);
        e1[q] = *(const f32x4*)(P + 768 + T * 32 + q * 8 + h4);
        e2[q] = *(const f32x4*)(P + 896 + T * 32 + q * 8 + h4);
      }
    } else if (INIT == 2) {
#pragma unroll
      for (int q = 0; q < 4; ++q) {
        e0[q] = *(const f32x4*)(P + 1856 + T * 32 + q * 8 + h4);
        e1[q] = *(const f32x4*)(P + 1920 + T * 32 + q * 8 + h4);
        e2[q] = *(const f32x4*)(P + 1984 + T * 32 + q * 8 + h4);
      }
    }
    __builtin_amdgcn_s_setprio(1);
#pragma unroll
    for (int pt = 0; pt < 2; ++pt) {
      f32x16 s;
#pragma unroll
      for (int q = 0; q < 4; ++q) {
        f32x4 vq = bq[q];
        if (INIT == 1)
          vq += px[pt][0] * e0[q] + px[pt][1] * e1[q] + px[pt][2] * e2[q];
        if (INIT == 2) {
          const int ray = (wbase + pt * 32) >> 7;   // wave-uniform
          vq += vw2[ray * 3] * e0[q] + vw2[ray * 3 + 1] * e1[q]
              + vw2[ray * 3 + 2] * e2[q];
        }
#pragma unroll
        for (int e3 = 0; e3 < 4; ++e3) s[q * 4 + e3] = vq[e3];
      }
      acc[pt][T] = __builtin_amdgcn_mfma_f32_32x32x16_f16(A[0], B[pt][KH * 4 + 0],
                                                          s, 0, 0, 0);
    }
#pragma unroll
    for (int i = 1; i < 4; ++i)
#pragma unroll
      for (int pt = 0; pt < 2; ++pt)
        acc[pt][T] = __builtin_amdgcn_mfma_f32_32x32x16_f16(
            A[i], B[pt][KH * 4 + i], acc[pt][T], 0, 0, 0);
    __builtin_amdgcn_s_setprio(0);
  } else {
    __builtin_amdgcn_s_setprio(1);
#pragma unroll
    for (int i = 0; i < 4; ++i)
#pragma unroll
      for (int pt = 0; pt < 2; ++pt)
        acc[pt][T] = __builtin_amdgcn_mfma_f32_32x32x16_f16(
            A[i], B[pt][KH * 4 + i], acc[pt][T], 0, 0, 0);
    __builtin_amdgcn_s_setprio(0);
  }
}

// acc -> next layer's B. B[pt][m] = packRelu of acc[pt][m>>1] regs 8*(m&1)+0..7
// (identity reg order — the klog32 weight permutation absorbs the layout).
template<int NM>
__device__ __forceinline__ void toB32(const f32x16 acc[2][4], f16x8 B[2][8]) {
#pragma unroll
  for (int pt = 0; pt < 2; ++pt)
#pragma unroll
    for (int m = 0; m < NM; ++m) {
      const int s = (m & 1) * 8;
      f32x4 v0, v1;
#pragma unroll
      for (int e3 = 0; e3 < 4; ++e3) {
        v0[e3] = acc[pt][m >> 1][s + e3];
        v1[e3] = acc[pt][m >> 1][s + 4 + e3];
      }
      B[pt][m] = packRelu(v0, v1);
    }
}

// ---------------------------------------------------------------------------
// Main: 512 threads, __launch_bounds__(512,2), grid 512 — blessed config.
// 512 pts/block, 8 waves x 64 pts (2 pt-tiles of 32), full 128-och/wave via
// 32x32x16 MFMA. Zero act-LDS, one barrier, chunk ping-pong Aa/Ab.
// ---------------------------------------------------------------------------
__global__ __launch_bounds__(512, 2) void nerf_main(
    const float* __restrict__ pos, const float* __restrict__ view,
    const char* __restrict__ ws, float* __restrict__ out) {
  __shared__ __align__(16) float Lp[2560 + 1536 + 16];  // params | pos | view
  const int t = threadIdx.x, lane = t & 63, w = t >> 6;
  const int c32 = lane & 31;
  const int h4 = ((lane >> 5) << 2), h8 = ((lane >> 5) << 3);
  const int base = blockIdx.x * 512;   // 512 points per block
  const int wbase = w * 64;            // 64 points per wave
  const float* P = Lp;
  float* Lpos = Lp + 2560;
  float* Lvw = Lp + 4096;

  for (int i = t; i < 2560; i += 512) Lp[i] = ((const float*)(ws + WS_PARAMS))[i];
  for (int i = t; i < 1536; i += 512) Lpos[i] = pos[base * 3 + i];
  if (t < 12) Lvw[t] = view[(base >> 7) * 3 + t];
  __syncthreads();

  f16x8 Aa[4], Ab[4];
  loadF4(Aa, ws + 0, 0, lane);         // L1 chunk0 — in flight during L0

  float px[2][3];
#pragma unroll
  for (int pt = 0; pt < 2; ++pt) {
    const int lp = wbase + pt * 32 + c32;
#pragma unroll
    for (int d = 0; d < 3; ++d) px[pt][d] = Lpos[lp * 3 + d];
  }

  // ---- L0: build L1's B-frags directly (natural k: ch = 16m + 8h + j) ----
  f16x8 B[2][8];
#pragma unroll
  for (int m = 0; m < 8; ++m) {
    const int chb = m * 16 + h8;
    const f32x4 b0  = *(const f32x4*)(P + chb),       b1  = *(const f32x4*)(P + chb + 4);
    const f32x4 w00 = *(const f32x4*)(P + 128 + chb), w01 = *(const f32x4*)(P + 128 + chb + 4);
    const f32x4 w10 = *(const f32x4*)(P + 256 + chb), w11 = *(const f32x4*)(P + 256 + chb + 4);
    const f32x4 w20 = *(const f32x4*)(P + 384 + chb), w21 = *(const f32x4*)(P + 384 + chb + 4);
#pragma unroll
    for (int pt = 0; pt < 2; ++pt) {
      const f32x4 v0 = b0 + px[pt][0] * w00 + px[pt][1] * w10 + px[pt][2] * w20;
      const f32x4 v1 = b1 + px[pt][0] * w01 + px[pt][1] * w11 + px[pt][2] * w21;
      B[pt][m] = packRelu(v0, v1);
    }
  }

  f32x16 acc[2][4];

  // chunk q: (T=q>>1, KH=q&1), frags fb=4q; preload next chunk into the
  // other buffer; chunk 7 preloads the NEXT layer's chunk 0.
#define QCE(T_, KH_, img_, fb, BIAS, INIT_)                                    \
  loadF4(Ab, img_, fb, lane);                                                  \
  qL32<T_, KH_, INIT_>(B, acc, Aa, P, px, Lvw, BIAS, h4, wbase);
#define QCO(T_, KH_, img_, fb, BIAS, INIT_)                                    \
  loadF4(Aa, img_, fb, lane);                                                  \
  qL32<T_, KH_, INIT_>(B, acc, Ab, P, px, Lvw, BIAS, h4, wbase);
#define DLAYER(img_, imgNext, BIAS, INIT_)                                     \
  QCE(0, 0, img_,  4, BIAS, INIT_) QCO(0, 1, img_,  8, BIAS, INIT_)            \
  QCE(1, 0, img_, 12, BIAS, INIT_) QCO(1, 1, img_, 16, BIAS, INIT_)            \
  QCE(2, 0, img_, 20, BIAS, INIT_) QCO(2, 1, img_, 24, BIAS, INIT_)            \
  QCE(3, 0, img_, 28, BIAS, INIT_) QCO(3, 1, imgNext, 0, BIAS, INIT_)

  DLAYER(ws +      0, ws +  32768, 1024, 0) toB32<8>(acc, B);  // L1
  DLAYER(ws +  32768, ws +  65536, 1152, 0) toB32<8>(acc, B);  // L2
  DLAYER(ws +  65536, ws +  98304, 1280, 0) toB32<8>(acc, B);  // L3
  DLAYER(ws +  98304, ws + 131072, 1408, 0) toB32<8>(acc, B);  // L4
  DLAYER(ws + 131072, ws + 163840,  512, 1) toB32<8>(acc, B);  // L5 (skip)
  DLAYER(ws + 163840, ws + 196608, 1536, 0) toB32<8>(acc, B);  // L6
  DLAYER(ws + 196608, ws + 229376, 1664, 0)                    // L7 (-> C0 ch0)
#undef DLAYER
#undef QCE
#undef QCO

  // ---- sigma from L7 acc (f32, relu'd): och = 32T + (reg&3)+8*(reg>>2)+4h ----
  float sig[2];
#pragma unroll
  for (int pt = 0; pt < 2; ++pt) {
    float s = 0.f;
#pragma unroll
    for (int T = 0; T < 4; ++T)
#pragma unroll
      for (int q = 0; q < 4; ++q) {
        const f32x4 wq = *(const f32x4*)(P + 2176 + T * 32 + q * 8 + h4);
#pragma unroll
        for (int e3 = 0; e3 < 4; ++e3)
          s += fmaxf(acc[pt][T][q * 4 + e3], 0.f) * wq[e3];
      }
    s += __shfl_xor(s, 32);
    sig[pt] = s + P[2304];
  }
  toB32<8>(acc, B);                                            // h7 -> C0 B

  // ---- C0 (och 64, K=128): 4 chunks; C0 chunk0 already in Aa ----
  loadF4(Ab, ws + 229376,  4, lane);
  qL32<0, 0, 2>(B, acc, Aa, P, px, Lvw, 1792, h4, wbase);
  loadF4(Aa, ws + 229376,  8, lane);
  qL32<0, 1, 2>(B, acc, Ab, P, px, Lvw, 1792, h4, wbase);
  loadF4(Ab, ws + 229376, 12, lane);
  qL32<1, 0, 2>(B, acc, Aa, P, px, Lvw, 1792, h4, wbase);
  loadF4(Aa, ws + 245760,  0, lane);                           // C1 ch0
  qL32<1, 1, 2>(B, acc, Ab, P, px, Lvw, 1792, h4, wbase);
  toB32<4>(acc, B);                                            // C0 -> B[0..3]

  // ---- C1 (64x64, K=64): 2 chunks ----
  loadF4(Ab, ws + 245760, 4, lane);
  qL32<0, 0, 0>(B, acc, Aa, P, px, Lvw, 2048, h4, wbase);
  loadF4(Aa, ws + 253952, 0, lane);                            // C2 ch0
  qL32<1, 0, 0>(B, acc, Ab, P, px, Lvw, 2048, h4, wbase);
  toB32<4>(acc, B);                                            // C1 -> B[0..3]

  // ---- C2 (64x64, K=64): 2 chunks ----
  loadF4(Ab, ws + 253952, 4, lane);
  qL32<0, 0, 0>(B, acc, Aa, P, px, Lvw, 2112, h4, wbase);
  qL32<1, 0, 0>(B, acc, Ab, P, px, Lvw, 2112, h4, wbase);

  // ---- rgb from C2 acc (T 0..1); reduce across halves; lanes h==0 store ----
#pragma unroll
  for (int pt = 0; pt < 2; ++pt) {
    float a0 = 0.f, a1 = 0.f, a2 = 0.f;
#pragma unroll
    for (int T = 0; T < 2; ++T)
#pragma unroll
      for (int q = 0; q < 4; ++q) {
        const int ob = T * 32 + q * 8 + h4;
        const f32x4 r0 = *(const f32x4*)(P + 2308 + ob);
        const f32x4 r1 = *(const f32x4*)(P + 2372 + ob);
        const f32x4 r2 = *(const f32x4*)(P + 2436 + ob);
#pragma unroll
        for (int e3 = 0; e3 < 4; ++e3) {
          const float h = fmaxf(acc[pt][T][q * 4 + e3], 0.f);
          a0 += h * r0[e3]; a1 += h * r1[e3]; a2 += h * r2[e3];
        }
      }
    a0 += __shfl_xor(a0, 32);
    a1 += __shfl_xor(a1, 32);
    a2 += __shfl_xor(a2, 32);
    if (lane < 32) {
      float4 o;
      o.x = a0 + P[2500]; o.y = a1 + P[2501]; o.z = a2 + P[2502]; o.w = sig[pt];
      *(float4*)(out + (base + wbase + pt * 32 + c32) * 4) = o;
    }
  }
}

extern "C" void kernel_launch(void* const* d_in, const int* in_sizes, int n_in,
                              void* d_out, int out_size, void* d_ws, size_t ws_size,
                              hipStream_t stream) {
  Ptrs ptrs;
  for (int i = 0; i < 29; ++i) ptrs.p[i] = (const float*)d_in[i];
  char* ws = (char*)d_ws;
  nerf_prep<<<513, 256, 0, stream>>>(ptrs, ws);
  nerf_main<<<512, 512, 0, stream>>>((const float*)d_in[0], (const float*)d_in[2],
                                     ws, (float*)d_out);
}

// Round 18
// 80.931 us; speedup vs baseline: 1.1731x; 1.1731x over previous
//
#include <hip/hip_runtime.h>

typedef _Float16 f16;
typedef _Float16 f16x8 __attribute__((ext_vector_type(8)));
typedef __fp16 hf16x2 __attribute__((ext_vector_type(2)));
typedef float f32x4 __attribute__((ext_vector_type(4)));
typedef float f32x16 __attribute__((ext_vector_type(16)));

// ---------------- d_ws layout (32x32x16 MFMA fragment order) ----------------
// [0, 262144) : f16 weight images, per-lane A-fragment order for
//   mfma_f32_32x32x16_f16. frag f = T*nks + m at imgbase + (f*64+lane)*16 + j*2
//   holds W[k_logical][och_out = 32T + (lane&31)], natural k_raw = 16m +
//   8*(lane>>5) + j.
//     k_logical = k_raw          for L1 (input built raw by L0)
//     k_logical = klog32(k_raw)  for L2..L7, C0, C1, C2 (in-register chaining;
//       C row=(reg&3)+8*(reg>>2)+4*(lane>>5) vs B k=8*(lane>>5)+j mismatch is
//       exactly a swap of bits 2<->3 of the within-16 k index)
//   L1..L7 (128x128, nks=8): i*32768 | C0h (64x128): 229376
//   C1 (64x64, nks=4): 245760 | C2: 253952
// [262144, +10240) : fp32 params block (identical to R11..R17):
//   0 b0f[128] | 128 W0p[3][128] | 512 b5f[128] | 640 W5p[3][128]
//   1024 db1 1152 db2 1280 db3 1408 db4 1536 db6 1664 db7 (x128)
//   1792 cb0[64] | 1856 cWv[3][64] | 2048 cb1[64] | 2112 cb2[64]
//   2176 sW[128] | 2304 sb | 2308 rWT[3][64] | 2500 rb[3]
#define WS_PARAMS 262144

struct Ptrs { const float* p[29]; };

__device__ __forceinline__ int klog32(int q) {
  return (q & ~12) | ((q & 4) << 1) | ((q & 8) >> 1);
}

// ---------------------------------------------------------------------------
// Prepass (verbatim from passing R17)
// ---------------------------------------------------------------------------
__global__ void nerf_prep(Ptrs ptrs, char* __restrict__ ws) {
  const int t = threadIdx.x;
  if (blockIdx.x == 0) {
    float* P = (float*)(ws + WS_PARAMS);
    const float* cond = ptrs.p[1];
    const float* dW0 = ptrs.p[3];  const float* db0 = ptrs.p[4];
    const float* dW5 = ptrs.p[13]; const float* db5 = ptrs.p[14];
    if (t < 128) {
      float a0 = db0[t], a5 = db5[t];
      for (int k = 0; k < 64; ++k) {
        const float c = cond[k];
        a0 += c * dW0[(3 + k) * 128 + t];
        a5 += c * dW5[(3 + k) * 128 + t];
      }
      P[t] = a0;          // b0f
      P[512 + t] = a5;    // b5f
      for (int k = 0; k < 3; ++k) {
        P[128 + k * 128 + t] = dW0[k * 128 + t];   // W0p
        P[640 + k * 128 + t] = dW5[k * 128 + t];   // W5p
      }
      P[1024 + t] = ptrs.p[6][t];    // db1
      P[1152 + t] = ptrs.p[8][t];    // db2
      P[1280 + t] = ptrs.p[10][t];   // db3
      P[1408 + t] = ptrs.p[12][t];   // db4
      P[1536 + t] = ptrs.p[16][t];   // db6
      P[1664 + t] = ptrs.p[18][t];   // db7
      P[2176 + t] = ptrs.p[19][t];   // sW
    }
    if (t < 64) {
      P[1792 + t] = ptrs.p[22][t];   // cb0
      for (int k = 0; k < 3; ++k)    // cWv = cW0 rows 128..130
        P[1856 + k * 64 + t] = ptrs.p[21][(128 + k) * 64 + t];
      P[2048 + t] = ptrs.p[24][t];   // cb1
      P[2112 + t] = ptrs.p[26][t];   // cb2
      for (int c = 0; c < 3; ++c)    // rWT[3][64]
        P[2308 + c * 64 + t] = ptrs.p[27][t * 3 + c];
    }
    if (t == 0) {
      P[2304] = ptrs.p[20][0];                 // sb
      P[2500] = ptrs.p[28][0];
      P[2501] = ptrs.p[28][1];
      P[2502] = ptrs.p[28][2];                 // rb
    }
    if (t < 3)  P[2305 + t] = 0.f;
    if (t < 57) P[2503 + t] = 0.f;
    return;
  }
  // 131072 f16 weight-fragment elements across blocks 1..512
  const int e = (blockIdx.x - 1) * 256 + t;
  float v; int dst;
  if (e < 114688) {                       // L1..L7 (128x128, 32 frags each)
    const int img = e >> 14, o = e & 16383;
    const int j = o & 7, lane = (o >> 3) & 63, m = (o >> 9) & 7, T = o >> 12;
    const int kraw = m * 16 + ((lane >> 5) << 3) + j;
    const int k = (img == 0) ? kraw : klog32(kraw);
    const int och = T * 32 + (lane & 31);
    v = ptrs.p[5 + 2 * img][(k + (img == 4 ? 67 : 0)) * 128 + och];
    dst = img * 32768 + (((T * 8 + m) * 64 + lane) << 4) + (j << 1);
  } else if (e < 122880) {                // C0h (64x128, 16 frags)
    const int o = e - 114688;
    const int j = o & 7, lane = (o >> 3) & 63, m = (o >> 9) & 7, T = o >> 12;
    const int k = klog32(m * 16 + ((lane >> 5) << 3) + j);
    const int och = T * 32 + (lane & 31);
    v = ptrs.p[21][k * 64 + och];
    dst = 229376 + (((T * 8 + m) * 64 + lane) << 4) + (j << 1);
  } else if (e < 126976) {                // C1 (64x64, 8 frags)
    const int o = e - 122880;
    const int j = o & 7, lane = (o >> 3) & 63, m = (o >> 9) & 3, T = o >> 11;
    const int k = klog32(m * 16 + ((lane >> 5) << 3) + j);
    const int och = T * 32 + (lane & 31);
    v = ptrs.p[23][k * 64 + och];
    dst = 245760 + (((T * 4 + m) * 64 + lane) << 4) + (j << 1);
  } else {                                // C2 (64x64, 8 frags)
    const int o = e - 126976;
    const int j = o & 7, lane = (o >> 3) & 63, m = (o >> 9) & 3, T = o >> 11;
    const int k = klog32(m * 16 + ((lane >> 5) << 3) + j);
    const int och = T * 32 + (lane & 31);
    v = ptrs.p[25][k * 64 + och];
    dst = 253952 + (((T * 4 + m) * 64 + lane) << 4) + (j << 1);
  }
  *(f16*)(ws + dst) = (f16)v;
}

// ---------------------------------------------------------------------------
// helpers
// ---------------------------------------------------------------------------
__device__ __forceinline__ void loadF4(f16x8* A, const char* __restrict__ img,
                                       int fb, int lane) {
#pragma unroll
  for (int i = 0; i < 4; ++i)
    A[i] = *(const f16x8*)(img + (((fb + i) * 64 + lane) << 4));
}

// pack two f32x4 -> f16x8 via cvt_pkrtz, then packed relu
__device__ __forceinline__ f16x8 packRelu(const f32x4 v0, const f32x4 v1) {
  const hf16x2 p0 = __builtin_amdgcn_cvt_pkrtz(v0[0], v0[1]);
  const hf16x2 p1 = __builtin_amdgcn_cvt_pkrtz(v0[2], v0[3]);
  const hf16x2 p2 = __builtin_amdgcn_cvt_pkrtz(v1[0], v1[1]);
  const hf16x2 p3 = __builtin_amdgcn_cvt_pkrtz(v1[2], v1[3]);
  f16x8 hb;
  hb[0] = (f16)p0[0]; hb[1] = (f16)p0[1]; hb[2] = (f16)p1[0]; hb[3] = (f16)p1[1];
  hb[4] = (f16)p2[0]; hb[5] = (f16)p2[1]; hb[6] = (f16)p3[0]; hb[7] = (f16)p3[1];
#pragma unroll
  for (int e2 = 0; e2 < 8; ++e2)
    hb[e2] = hb[e2] > (f16)0.f ? hb[e2] : (f16)0.f;
  return hb;
}

// ---------------------------------------------------------------------------
// Chunk: och-tile T, k-half KH (k-steps m = 4KH..4KH+3), 8 MFMAs (2 pt-tiles).
// KH==0 seeds acc via the MFMA C operand (bias16, + pos/view for INIT 1/2).
// ---------------------------------------------------------------------------
template<int T, int KH, int INIT>
__device__ __forceinline__ void qL32(const f16x8 B[2][8], f32x16 acc[2][4],
                                     const f16x8* A, const float* __restrict__ P,
                                     const float px[2][3],
                                     const float* __restrict__ vw2,
                                     int biasOff, int h4, int wbase) {
  if (KH == 0) {
    f32x4 bq[4];
#pragma unroll
    for (int q = 0; q < 4; ++q)
      bq[q] = *(const f32x4*)(P + biasOff + T * 32 + q * 8 + h4);
    f32x4 e0[4], e1[4], e2[4];
    if (INIT == 1) {
#pragma unroll
      for (int q = 0; q < 4; ++q) {
        e0[q] = *(const f32x4*)(P + 640 + T * 32 + q * 8 + h4);
        e1[q] = *(const f32x4*)(P + 768 + T * 32 + q * 8 + h4);
        e2[q] = *(const f32x4*)(P + 896 + T * 32 + q * 8 + h4);
      }
    } else if (INIT == 2) {
#pragma unroll
      for (int q = 0; q < 4; ++q) {
        e0[q] = *(const f32x4*)(P + 1856 + T * 32 + q * 8 + h4);
        e1[q] = *(const f32x4*)(P + 1920 + T * 32 + q * 8 + h4);
        e2[q] = *(const f32x4*)(P + 1984 + T * 32 + q * 8 + h4);
      }
    }
    __builtin_amdgcn_s_setprio(1);
#pragma unroll
    for (int pt = 0; pt < 2; ++pt) {
      f32x16 s;
#pragma unroll
      for (int q = 0; q < 4; ++q) {
        f32x4 vq = bq[q];
        if (INIT == 1)
          vq += px[pt][0] * e0[q] + px[pt][1] * e1[q] + px[pt][2] * e2[q];
        if (INIT == 2) {
          const int ray = (wbase + pt * 32) >> 7;   // wave-uniform
          vq += vw2[ray * 3] * e0[q] + vw2[ray * 3 + 1] * e1[q]
              + vw2[ray * 3 + 2] * e2[q];
        }
#pragma unroll
        for (int e3 = 0; e3 < 4; ++e3) s[q * 4 + e3] = vq[e3];
      }
      acc[pt][T] = __builtin_amdgcn_mfma_f32_32x32x16_f16(A[0], B[pt][KH * 4 + 0],
                                                          s, 0, 0, 0);
    }
#pragma unroll
    for (int i = 1; i < 4; ++i)
#pragma unroll
      for (int pt = 0; pt < 2; ++pt)
        acc[pt][T] = __builtin_amdgcn_mfma_f32_32x32x16_f16(
            A[i], B[pt][KH * 4 + i], acc[pt][T], 0, 0, 0);
    __builtin_amdgcn_s_setprio(0);
  } else {
    __builtin_amdgcn_s_setprio(1);
#pragma unroll
    for (int i = 0; i < 4; ++i)
#pragma unroll
      for (int pt = 0; pt < 2; ++pt)
        acc[pt][T] = __builtin_amdgcn_mfma_f32_32x32x16_f16(
            A[i], B[pt][KH * 4 + i], acc[pt][T], 0, 0, 0);
    __builtin_amdgcn_s_setprio(0);
  }
}

// Incremental per-tile convert: acc[pt][T] -> Bout[pt][2T], [2T+1].
// Releases the tile's acc registers immediately (spill fix vs R17).
template<int T>
__device__ __forceinline__ void toBtile(const f32x16 acc[2][4], f16x8 B[2][8]) {
#pragma unroll
  for (int pt = 0; pt < 2; ++pt) {
    f32x4 v0, v1, v2, v3;
#pragma unroll
    for (int e3 = 0; e3 < 4; ++e3) {
      v0[e3] = acc[pt][T][e3];
      v1[e3] = acc[pt][T][4 + e3];
      v2[e3] = acc[pt][T][8 + e3];
      v3[e3] = acc[pt][T][12 + e3];
    }
    B[pt][2 * T]     = packRelu(v0, v1);
    B[pt][2 * T + 1] = packRelu(v2, v3);
  }
}

// full-acc convert (used after sigma for L7 -> C0 input)
template<int NM>
__device__ __forceinline__ void toB32(const f32x16 acc[2][4], f16x8 B[2][8]) {
#pragma unroll
  for (int pt = 0; pt < 2; ++pt)
#pragma unroll
    for (int m = 0; m < NM; ++m) {
      const int s = (m & 1) * 8;
      f32x4 v0, v1;
#pragma unroll
      for (int e3 = 0; e3 < 4; ++e3) {
        v0[e3] = acc[pt][m >> 1][s + e3];
        v1[e3] = acc[pt][m >> 1][s + 4 + e3];
      }
      B[pt][m] = packRelu(v0, v1);
    }
}

// ---------------------------------------------------------------------------
// Main: 512 threads, __launch_bounds__(512,2), grid 512 — blessed config.
// 512 pts/block, 8 waves x 64 pts, 32x32x16 MFMA, zero act-LDS, one barrier.
// B ping-pongs between named arrays Bx/By (macro args, static indexing);
// per-tile incremental toB keeps only ~32 acc regs live (R17 spill fix).
// ---------------------------------------------------------------------------
__global__ __launch_bounds__(512, 2) void nerf_main(
    const float* __restrict__ pos, const float* __restrict__ view,
    const char* __restrict__ ws, float* __restrict__ out) {
  __shared__ __align__(16) float Lp[2560 + 1536 + 16];  // params | pos | view
  const int t = threadIdx.x, lane = t & 63, w = t >> 6;
  const int c32 = lane & 31;
  const int h4 = ((lane >> 5) << 2), h8 = ((lane >> 5) << 3);
  const int base = blockIdx.x * 512;   // 512 points per block
  const int wbase = w * 64;            // 64 points per wave
  const float* P = Lp;
  float* Lpos = Lp + 2560;
  float* Lvw = Lp + 4096;

  for (int i = t; i < 2560; i += 512) Lp[i] = ((const float*)(ws + WS_PARAMS))[i];
  for (int i = t; i < 1536; i += 512) Lpos[i] = pos[base * 3 + i];
  if (t < 12) Lvw[t] = view[(base >> 7) * 3 + t];
  __syncthreads();

  f16x8 Aa[4], Ab[4];
  loadF4(Aa, ws + 0, 0, lane);         // L1 chunk0 — in flight during L0

  float px[2][3];
#pragma unroll
  for (int pt = 0; pt < 2; ++pt) {
    const int lp = wbase + pt * 32 + c32;
#pragma unroll
    for (int d = 0; d < 3; ++d) px[pt][d] = Lpos[lp * 3 + d];
  }

  // ---- L0: build L1's B-frags directly (natural k: ch = 16m + 8h + j) ----
  f16x8 Bx[2][8], By[2][8];
#pragma unroll
  for (int m = 0; m < 8; ++m) {
    const int chb = m * 16 + h8;
    const f32x4 b0  = *(const f32x4*)(P + chb),       b1  = *(const f32x4*)(P + chb + 4);
    const f32x4 w00 = *(const f32x4*)(P + 128 + chb), w01 = *(const f32x4*)(P + 128 + chb + 4);
    const f32x4 w10 = *(const f32x4*)(P + 256 + chb), w11 = *(const f32x4*)(P + 256 + chb + 4);
    const f32x4 w20 = *(const f32x4*)(P + 384 + chb), w21 = *(const f32x4*)(P + 384 + chb + 4);
#pragma unroll
    for (int pt = 0; pt < 2; ++pt) {
      const f32x4 v0 = b0 + px[pt][0] * w00 + px[pt][1] * w10 + px[pt][2] * w20;
      const f32x4 v1 = b1 + px[pt][0] * w01 + px[pt][1] * w11 + px[pt][2] * w21;
      Bx[pt][m] = packRelu(v0, v1);
    }
  }

  f32x16 acc[2][4];

  // Layer: 8 chunks (T,KH); chunk q uses Aa/Ab ping-pong with one-ahead
  // loads; per-tile toB into Bout right after each tile's second chunk.
#define DLAYER(Bin, Bout, img_, imgNext, BIAS, INIT_)                          \
  loadF4(Ab, img_,  4, lane); qL32<0,0,INIT_>(Bin, acc, Aa, P, px, Lvw, BIAS, h4, wbase); \
  loadF4(Aa, img_,  8, lane); qL32<0,1,INIT_>(Bin, acc, Ab, P, px, Lvw, BIAS, h4, wbase); \
  toBtile<0>(acc, Bout);                                                       \
  loadF4(Ab, img_, 12, lane); qL32<1,0,INIT_>(Bin, acc, Aa, P, px, Lvw, BIAS, h4, wbase); \
  loadF4(Aa, img_, 16, lane); qL32<1,1,INIT_>(Bin, acc, Ab, P, px, Lvw, BIAS, h4, wbase); \
  toBtile<1>(acc, Bout);                                                       \
  loadF4(Ab, img_, 20, lane); qL32<2,0,INIT_>(Bin, acc, Aa, P, px, Lvw, BIAS, h4, wbase); \
  loadF4(Aa, img_, 24, lane); qL32<2,1,INIT_>(Bin, acc, Ab, P, px, Lvw, BIAS, h4, wbase); \
  toBtile<2>(acc, Bout);                                                       \
  loadF4(Ab, img_, 28, lane); qL32<3,0,INIT_>(Bin, acc, Aa, P, px, Lvw, BIAS, h4, wbase); \
  loadF4(Aa, imgNext, 0, lane); qL32<3,1,INIT_>(Bin, acc, Ab, P, px, Lvw, BIAS, h4, wbase); \
  toBtile<3>(acc, Bout);

  // L7: no per-tile toB (sigma needs the full f32 acc)
#define DLAYER_NOOUT(Bin, img_, imgNext, BIAS, INIT_)                          \
  loadF4(Ab, img_,  4, lane); qL32<0,0,INIT_>(Bin, acc, Aa, P, px, Lvw, BIAS, h4, wbase); \
  loadF4(Aa, img_,  8, lane); qL32<0,1,INIT_>(Bin, acc, Ab, P, px, Lvw, BIAS, h4, wbase); \
  loadF4(Ab, img_, 12, lane); qL32<1,0,INIT_>(Bin, acc, Aa, P, px, Lvw, BIAS, h4, wbase); \
  loadF4(Aa, img_, 16, lane); qL32<1,1,INIT_>(Bin, acc, Ab, P, px, Lvw, BIAS, h4, wbase); \
  loadF4(Ab, img_, 20, lane); qL32<2,0,INIT_>(Bin, acc, Aa, P, px, Lvw, BIAS, h4, wbase); \
  loadF4(Aa, img_, 24, lane); qL32<2,1,INIT_>(Bin, acc, Ab, P, px, Lvw, BIAS, h4, wbase); \
  loadF4(Ab, img_, 28, lane); qL32<3,0,INIT_>(Bin, acc, Aa, P, px, Lvw, BIAS, h4, wbase); \
  loadF4(Aa, imgNext, 0, lane); qL32<3,1,INIT_>(Bin, acc, Ab, P, px, Lvw, BIAS, h4, wbase);

  DLAYER(Bx, By, ws +      0, ws +  32768, 1024, 0)   // L1
  DLAYER(By, Bx, ws +  32768, ws +  65536, 1152, 0)   // L2
  DLAYER(Bx, By, ws +  65536, ws +  98304, 1280, 0)   // L3
  DLAYER(By, Bx, ws +  98304, ws + 131072, 1408, 0)   // L4
  DLAYER(Bx, By, ws + 131072, ws + 163840,  512, 1)   // L5 (skip)
  DLAYER(By, Bx, ws + 163840, ws + 196608, 1536, 0)   // L6
  DLAYER_NOOUT(Bx, ws + 196608, ws + 229376, 1664, 0) // L7 (preloads C0 ch0)
#undef DLAYER
#undef DLAYER_NOOUT

  // ---- sigma from L7 acc (f32, relu'd): och = 32T + (reg&3)+8*(reg>>2)+4h ----
  float sig[2];
#pragma unroll
  for (int pt = 0; pt < 2; ++pt) {
    float s = 0.f;
#pragma unroll
    for (int T = 0; T < 4; ++T)
#pragma unroll
      for (int q = 0; q < 4; ++q) {
        const f32x4 wq = *(const f32x4*)(P + 2176 + T * 32 + q * 8 + h4);
#pragma unroll
        for (int e3 = 0; e3 < 4; ++e3)
          s += fmaxf(acc[pt][T][q * 4 + e3], 0.f) * wq[e3];
      }
    s += __shfl_xor(s, 32);
    sig[pt] = s + P[2304];
  }
  toB32<8>(acc, By);                                   // h7 -> C0 input

  // ---- C0 (och 64, K=128): 4 chunks; ch0 already in Aa; out -> Bx ----
  loadF4(Ab, ws + 229376,  4, lane);
  qL32<0, 0, 2>(By, acc, Aa, P, px, Lvw, 1792, h4, wbase);
  loadF4(Aa, ws + 229376,  8, lane);
  qL32<0, 1, 2>(By, acc, Ab, P, px, Lvw, 1792, h4, wbase);
  toBtile<0>(acc, Bx);
  loadF4(Ab, ws + 229376, 12, lane);
  qL32<1, 0, 2>(By, acc, Aa, P, px, Lvw, 1792, h4, wbase);
  loadF4(Aa, ws + 245760,  0, lane);                   // C1 ch0
  qL32<1, 1, 2>(By, acc, Ab, P, px, Lvw, 1792, h4, wbase);
  toBtile<1>(acc, Bx);

  // ---- C1 (64x64, K=64): 2 chunks; out -> By ----
  loadF4(Ab, ws + 245760, 4, lane);
  qL32<0, 0, 0>(Bx, acc, Aa, P, px, Lvw, 2048, h4, wbase);
  toBtile<0>(acc, By);
  loadF4(Aa, ws + 253952, 0, lane);                    // C2 ch0
  qL32<1, 0, 0>(Bx, acc, Ab, P, px, Lvw, 2048, h4, wbase);
  toBtile<1>(acc, By);

  // ---- C2 (64x64, K=64): 2 chunks; rgb reads acc directly ----
  loadF4(Ab, ws + 253952, 4, lane);
  qL32<0, 0, 0>(By, acc, Aa, P, px, Lvw, 2112, h4, wbase);
  qL32<1, 0, 0>(By, acc, Ab, P, px, Lvw, 2112, h4, wbase);

  // ---- rgb from C2 acc (T 0..1); reduce across halves; lanes h==0 store ----
#pragma unroll
  for (int pt = 0; pt < 2; ++pt) {
    float a0 = 0.f, a1 = 0.f, a2 = 0.f;
#pragma unroll
    for (int T = 0; T < 2; ++T)
#pragma unroll
      for (int q = 0; q < 4; ++q) {
        const int ob = T * 32 + q * 8 + h4;
        const f32x4 r0 = *(const f32x4*)(P + 2308 + ob);
        const f32x4 r1 = *(const f32x4*)(P + 2372 + ob);
        const f32x4 r2 = *(const f32x4*)(P + 2436 + ob);
#pragma unroll
        for (int e3 = 0; e3 < 4; ++e3) {
          const float h = fmaxf(acc[pt][T][q * 4 + e3], 0.f);
          a0 += h * r0[e3]; a1 += h * r1[e3]; a2 += h * r2[e3];
        }
      }
    a0 += __shfl_xor(a0, 32);
    a1 += __shfl_xor(a1, 32);
    a2 += __shfl_xor(a2, 32);
    if (lane < 32) {
      float4 o;
      o.x = a0 + P[2500]; o.y = a1 + P[2501]; o.z = a2 + P[2502]; o.w = sig[pt];
      *(float4*)(out + (base + wbase + pt * 32 + c32) * 4) = o;
    }
  }
}

extern "C" void kernel_launch(void* const* d_in, const int* in_sizes, int n_in,
                              void* d_out, int out_size, void* d_ws, size_t ws_size,
                              hipStream_t stream) {
  Ptrs ptrs;
  for (int i = 0; i < 29; ++i) ptrs.p[i] = (const float*)d_in[i];
  char* ws = (char*)d_ws;
  nerf_prep<<<513, 256, 0, stream>>>(ptrs, ws);
  nerf_main<<<512, 512, 0, stream>>>((const float*)d_in[0], (const float*)d_in[2],
                                     ws, (float*)d_out);
}